// Round 2
// baseline (999.546 us; speedup 1.0000x reference)
//
#include <hip/hip_runtime.h>
#include <cstdint>

#define L_SEQ 2304
#define CDIM  512
#define NHEADS 8
#define HD    64
#define LL    ((size_t)L_SEQ * L_SEQ)

// ==================================================================
// QKV projection: out[b][h][l][d] = sum_c W[o][c]*(x[b][c][l]+pos[c][l]) + bias[o]
// where o = h*64+d.  grid (L/64, C/64, B*3), block 256.
__global__ __launch_bounds__(256) void qkv_gemm(
    const float* __restrict__ x, const float* __restrict__ pos,
    const float* __restrict__ Wq, const float* __restrict__ bq,
    const float* __restrict__ Wk, const float* __restrict__ bk,
    const float* __restrict__ Wv, const float* __restrict__ bv,
    float* __restrict__ q_t, float* __restrict__ k_t, float* __restrict__ v_t)
{
    const int l0 = blockIdx.x * 64;
    const int o0 = blockIdx.y * 64;
    const int b  = blockIdx.z / 3;
    const int w  = blockIdx.z % 3;
    const float* W    = (w == 0) ? Wq : (w == 1) ? Wk : Wv;
    const float* bias = (w == 0) ? bq : (w == 1) ? bk : bv;
    float* outp       = (w == 0) ? q_t : (w == 1) ? k_t : v_t;

    __shared__ float As[16][68];   // As[c][o-local], transposed W tile
    __shared__ float Xs[16][68];   // Xs[c][l-local]

    const int t  = threadIdx.x;
    const int ti = t & 15;        // o quad index
    const int tj = t >> 4;        // l quad index (0..15)
    float acc[4][4] = {};

    const float* xb = x + (size_t)b * CDIM * L_SEQ;

    for (int c0 = 0; c0 < CDIM; c0 += 16) {
        {   // W tile: 64 o x 16 c
            const int oi = t >> 2;
            const int cc = (t & 3) * 4;
            const float4 wv = *(const float4*)&W[(size_t)(o0 + oi) * CDIM + c0 + cc];
            As[cc + 0][oi] = wv.x;
            As[cc + 1][oi] = wv.y;
            As[cc + 2][oi] = wv.z;
            As[cc + 3][oi] = wv.w;
        }
        {   // X tile: 16 c x 64 l, fold x+pos here
            const int kk = t >> 4;
            const int j  = (t & 15) * 4;
            const size_t off = (size_t)(c0 + kk) * L_SEQ + l0 + j;
            float4 xv = *(const float4*)&xb[off];
            const float4 pv = *(const float4*)&pos[off];
            xv.x += pv.x; xv.y += pv.y; xv.z += pv.z; xv.w += pv.w;
            *(float4*)&Xs[kk][j] = xv;
        }
        __syncthreads();
        #pragma unroll
        for (int kk = 0; kk < 16; kk++) {
            const float4 a  = *(const float4*)&As[kk][ti * 4];
            const float4 bb = *(const float4*)&Xs[kk][tj * 4];
            const float av[4] = {a.x, a.y, a.z, a.w};
            const float bv4[4] = {bb.x, bb.y, bb.z, bb.w};
            #pragma unroll
            for (int i = 0; i < 4; i++)
                #pragma unroll
                for (int j = 0; j < 4; j++)
                    acc[i][j] += av[i] * bv4[j];
        }
        __syncthreads();
    }

    // epilogue: o0 is 64-aligned so whole block is one head; d = ti*4+i
    const int h = o0 >> 6;
    const float4 bi = *(const float4*)&bias[o0 + ti * 4];
    float* op = outp + ((size_t)b * NHEADS + h) * L_SEQ * HD;
    #pragma unroll
    for (int j = 0; j < 4; j++) {
        const int l = l0 + tj * 4 + j;
        float4 st;
        st.x = acc[0][j] + bi.x;
        st.y = acc[1][j] + bi.y;
        st.z = acc[2][j] + bi.z;
        st.w = acc[3][j] + bi.w;
        *(float4*)&op[(size_t)l * HD + ti * 4] = st;
    }
}

// ==================================================================
// Flash attention, fp32. Block = 64 q-rows of one (b,h). 256 threads.
// Thread (qr=t>>3, mg=t&7) owns rows {qr, qr+32}, cols/d-slice mg*8..mg*8+7.
// grid (L/64, B*NHEADS), block 256.
__global__ __launch_bounds__(256) void flash_attn(
    const float* __restrict__ q_t, const float* __restrict__ k_t,
    const float* __restrict__ v_t, const int* __restrict__ mask,
    const float* __restrict__ rel_table, float* __restrict__ attn_out)
{
    __shared__ float Kt[64][68];  // K transposed: Kt[d][m-local]
    __shared__ float Vs[64][68];  // Vs[m-local][d]
    __shared__ float Ps[64][65];  // P: Ps[row-local][m-local]
    __shared__ float rt[65];

    const int t  = threadIdx.x;
    const int bh = blockIdx.y;
    const int h  = bh & (NHEADS - 1);
    const int l0 = blockIdx.x * 64;

    const float* qp = q_t + (size_t)bh * L_SEQ * HD;
    const float* kp = k_t + (size_t)bh * L_SEQ * HD;
    const float* vp = v_t + (size_t)bh * L_SEQ * HD;
    const int* mp = mask + (size_t)h * LL;

    if (t < 65) rt[t] = rel_table[h * 65 + t];  // visible after first barrier

    const int qr = t >> 3;   // 0..31
    const int mg = t & 7;
    const int r0 = qr, r1 = qr + 32;

    // Q rows (pre-scaled by 1/sqrt(64)=0.125) into registers
    float q0r[8], q1r[8];
    {
        const float* p0 = &qp[(size_t)(l0 + r0) * HD + mg * 8];
        const float* p1 = &qp[(size_t)(l0 + r1) * HD + mg * 8];
        const float4 a0 = *(const float4*)p0;
        const float4 a1 = *(const float4*)(p0 + 4);
        const float4 c0 = *(const float4*)p1;
        const float4 c1 = *(const float4*)(p1 + 4);
        q0r[0]=a0.x*0.125f; q0r[1]=a0.y*0.125f; q0r[2]=a0.z*0.125f; q0r[3]=a0.w*0.125f;
        q0r[4]=a1.x*0.125f; q0r[5]=a1.y*0.125f; q0r[6]=a1.z*0.125f; q0r[7]=a1.w*0.125f;
        q1r[0]=c0.x*0.125f; q1r[1]=c0.y*0.125f; q1r[2]=c0.z*0.125f; q1r[3]=c0.w*0.125f;
        q1r[4]=c1.x*0.125f; q1r[5]=c1.y*0.125f; q1r[6]=c1.z*0.125f; q1r[7]=c1.w*0.125f;
    }

    float O0[8] = {}, O1[8] = {};
    float mrun0 = -1e30f, mrun1 = -1e30f;
    float lrun0 = 0.f, lrun1 = 0.f;

    for (int mt = 0; mt < L_SEQ / 64; mt++) {
        const int mb = mt * 64;
        __syncthreads();  // WAR: prev iter's PV must finish before restaging
        {   // stage K^T and V tiles
            const int col = (t & 15) * 4;
            const int rb  = t >> 4;
            #pragma unroll
            for (int r = 0; r < 4; r++) {
                const int row = r * 16 + rb;
                const float4 kv = *(const float4*)&kp[(size_t)(mb + row) * HD + col];
                Kt[col + 0][row] = kv.x;
                Kt[col + 1][row] = kv.y;
                Kt[col + 2][row] = kv.z;
                Kt[col + 3][row] = kv.w;
                const float4 vv = *(const float4*)&vp[(size_t)(mb + row) * HD + col];
                *(float4*)&Vs[row][col] = vv;
            }
        }
        __syncthreads();

        // ---- S = Q K^T : 2 rows x 8 cols per thread
        float s0[8] = {}, s1[8] = {};
        #pragma unroll
        for (int d8 = 0; d8 < 8; d8++) {
            #pragma unroll
            for (int dl = 0; dl < 8; dl++) {
                const int d = d8 * 8 + dl;
                const float q0 = __shfl(q0r[dl], d8, 8);
                const float q1 = __shfl(q1r[dl], d8, 8);
                const float4 ka = *(const float4*)&Kt[d][mg * 8];
                const float4 kb = *(const float4*)&Kt[d][mg * 8 + 4];
                const float kv[8] = {ka.x, ka.y, ka.z, ka.w, kb.x, kb.y, kb.z, kb.w};
                #pragma unroll
                for (int j = 0; j < 8; j++) { s0[j] += q0 * kv[j]; s1[j] += q1 * kv[j]; }
            }
        }

        // ---- relative positional bias (uniform for far-off-diagonal tiles)
        const int mcol = mb + mg * 8;
        const int td = l0 - mb;
        if (td >= 128) {
            const float bu = rt[64];
            #pragma unroll
            for (int j = 0; j < 8; j++) { s0[j] += bu; s1[j] += bu; }
        } else if (td <= -128) {
            const float bu = rt[0];
            #pragma unroll
            for (int j = 0; j < 8; j++) { s0[j] += bu; s1[j] += bu; }
        } else {
            const int lr0 = l0 + r0, lr1 = l0 + r1;
            #pragma unroll
            for (int j = 0; j < 8; j++) {
                int d0 = lr0 - (mcol + j); d0 = min(max(d0, -32), 32) + 32;
                int d1 = lr1 - (mcol + j); d1 = min(max(d1, -32), 32) + 32;
                s0[j] += rt[d0];
                s1[j] += rt[d1];
            }
        }

        // ---- mask (int32: harness passes bool as int); masked -> -1e9 after bias
        {
            const int* mr = mp + (size_t)(l0 + r0) * L_SEQ + mcol;
            const int4 ma0 = *(const int4*)mr;
            const int4 ma1 = *(const int4*)(mr + 4);
            const int4 mb0 = *(const int4*)(mr + (size_t)32 * L_SEQ);
            const int4 mb1 = *(const int4*)(mr + (size_t)32 * L_SEQ + 4);
            if (ma0.x == 0) s0[0] = -1e9f;
            if (ma0.y == 0) s0[1] = -1e9f;
            if (ma0.z == 0) s0[2] = -1e9f;
            if (ma0.w == 0) s0[3] = -1e9f;
            if (ma1.x == 0) s0[4] = -1e9f;
            if (ma1.y == 0) s0[5] = -1e9f;
            if (ma1.z == 0) s0[6] = -1e9f;
            if (ma1.w == 0) s0[7] = -1e9f;
            if (mb0.x == 0) s1[0] = -1e9f;
            if (mb0.y == 0) s1[1] = -1e9f;
            if (mb0.z == 0) s1[2] = -1e9f;
            if (mb0.w == 0) s1[3] = -1e9f;
            if (mb1.x == 0) s1[4] = -1e9f;
            if (mb1.y == 0) s1[5] = -1e9f;
            if (mb1.z == 0) s1[6] = -1e9f;
            if (mb1.w == 0) s1[7] = -1e9f;
        }

        // ---- online softmax (state replicated across the 8-lane row group)
        float mx0 = s0[0], mx1 = s1[0];
        #pragma unroll
        for (int j = 1; j < 8; j++) { mx0 = fmaxf(mx0, s0[j]); mx1 = fmaxf(mx1, s1[j]); }
        #pragma unroll
        for (int off = 1; off < 8; off <<= 1) {
            mx0 = fmaxf(mx0, __shfl_xor(mx0, off, 8));
            mx1 = fmaxf(mx1, __shfl_xor(mx1, off, 8));
        }
        const float mn0 = fmaxf(mrun0, mx0);
        const float mn1 = fmaxf(mrun1, mx1);
        const float al0 = __expf(mrun0 - mn0);
        const float al1 = __expf(mrun1 - mn1);
        mrun0 = mn0; mrun1 = mn1;
        float sum0 = 0.f, sum1 = 0.f;
        #pragma unroll
        for (int j = 0; j < 8; j++) {
            s0[j] = __expf(s0[j] - mn0); sum0 += s0[j];
            s1[j] = __expf(s1[j] - mn1); sum1 += s1[j];
        }
        #pragma unroll
        for (int off = 1; off < 8; off <<= 1) {
            sum0 += __shfl_xor(sum0, off, 8);
            sum1 += __shfl_xor(sum1, off, 8);
        }
        lrun0 = lrun0 * al0 + sum0;
        lrun1 = lrun1 * al1 + sum1;
        #pragma unroll
        for (int j = 0; j < 8; j++) { O0[j] *= al0; O1[j] *= al1; }
        #pragma unroll
        for (int j = 0; j < 8; j++) {
            Ps[r0][mg * 8 + j] = s0[j];
            Ps[r1][mg * 8 + j] = s1[j];
        }
        __syncthreads();

        // ---- O += P V
        #pragma unroll 8
        for (int mm = 0; mm < 64; mm++) {
            const float p0 = Ps[r0][mm];
            const float p1 = Ps[r1][mm];
            const float4 va = *(const float4*)&Vs[mm][mg * 8];
            const float4 vb = *(const float4*)&Vs[mm][mg * 8 + 4];
            const float vv[8] = {va.x, va.y, va.z, va.w, vb.x, vb.y, vb.z, vb.w};
            #pragma unroll
            for (int j = 0; j < 8; j++) { O0[j] += p0 * vv[j]; O1[j] += p1 * vv[j]; }
        }
    }

    const float i0 = 1.0f / lrun0;
    const float i1 = 1.0f / lrun1;
    float* op = attn_out + (size_t)bh * L_SEQ * HD;
    float4 st;
    st.x=O0[0]*i0; st.y=O0[1]*i0; st.z=O0[2]*i0; st.w=O0[3]*i0;
    *(float4*)&op[(size_t)(l0 + r0) * HD + mg * 8] = st;
    st.x=O0[4]*i0; st.y=O0[5]*i0; st.z=O0[6]*i0; st.w=O0[7]*i0;
    *(float4*)&op[(size_t)(l0 + r0) * HD + mg * 8 + 4] = st;
    st.x=O1[0]*i1; st.y=O1[1]*i1; st.z=O1[2]*i1; st.w=O1[3]*i1;
    *(float4*)&op[(size_t)(l0 + r1) * HD + mg * 8] = st;
    st.x=O1[4]*i1; st.y=O1[5]*i1; st.z=O1[6]*i1; st.w=O1[7]*i1;
    *(float4*)&op[(size_t)(l0 + r1) * HD + mg * 8 + 4] = st;
}

// ==================================================================
// Output projection + bias + residual: y[b][o][l] = x[b][o][l] + bo[o]
//   + sum_c Wo[o][c]*attn[b][c>>6][l][c&63].  grid (36, 8, 2), block 256.
__global__ __launch_bounds__(256) void out_gemm(
    const float* __restrict__ attn, const float* __restrict__ Wo,
    const float* __restrict__ bo, const float* __restrict__ x,
    float* __restrict__ y)
{
    const int l0 = blockIdx.x * 64;
    const int o0 = blockIdx.y * 64;
    const int b  = blockIdx.z;

    __shared__ float As[16][68];
    __shared__ float Xs[16][68];

    const int t  = threadIdx.x;
    const int ti = t & 15;
    const int tj = t >> 4;
    float acc[4][4] = {};

    const float* ab = attn + (size_t)b * NHEADS * L_SEQ * HD;

    for (int c0 = 0; c0 < CDIM; c0 += 16) {
        {
            const int oi = t >> 2;
            const int cc = (t & 3) * 4;
            const float4 wv = *(const float4*)&Wo[(size_t)(o0 + oi) * CDIM + c0 + cc];
            As[cc + 0][oi] = wv.x;
            As[cc + 1][oi] = wv.y;
            As[cc + 2][oi] = wv.z;
            As[cc + 3][oi] = wv.w;
        }
        {   // attn is (b,h,l,d); 4 consecutive c = 4 consecutive d (never crosses head)
            const int j   = t & 63;
            const int kkb = (t >> 6) * 4;
            const int c   = c0 + kkb;
            const int hh  = c >> 6;
            const int dd  = c & 63;
            const float4 av = *(const float4*)&ab[((size_t)hh * L_SEQ + l0 + j) * HD + dd];
            Xs[kkb + 0][j] = av.x;
            Xs[kkb + 1][j] = av.y;
            Xs[kkb + 2][j] = av.z;
            Xs[kkb + 3][j] = av.w;
        }
        __syncthreads();
        #pragma unroll
        for (int kk = 0; kk < 16; kk++) {
            const float4 a  = *(const float4*)&As[kk][ti * 4];
            const float4 bb = *(const float4*)&Xs[kk][tj * 4];
            const float av[4] = {a.x, a.y, a.z, a.w};
            const float bv4[4] = {bb.x, bb.y, bb.z, bb.w};
            #pragma unroll
            for (int i = 0; i < 4; i++)
                #pragma unroll
                for (int j = 0; j < 4; j++)
                    acc[i][j] += av[i] * bv4[j];
        }
        __syncthreads();
    }

    const float4 bi = *(const float4*)&bo[o0 + ti * 4];
    const float bia[4] = {bi.x, bi.y, bi.z, bi.w};
    #pragma unroll
    for (int i = 0; i < 4; i++) {
        const int o = o0 + ti * 4 + i;
        const size_t off = ((size_t)b * CDIM + o) * L_SEQ + l0 + tj * 4;
        const float4 xv = *(const float4*)&x[off];
        float4 st;
        st.x = acc[i][0] + bia[i] + xv.x;
        st.y = acc[i][1] + bia[i] + xv.y;
        st.z = acc[i][2] + bia[i] + xv.z;
        st.w = acc[i][3] + bia[i] + xv.w;
        *(float4*)&y[off] = st;
    }
}

// ==================================================================
// LayerNorm over channels, in place on y (B,C,L). grid 72, block 256:
// 64 positions/block, 4 channel-groups of 128 per position.
__global__ __launch_bounds__(256) void ln_kernel(
    float* __restrict__ y, const float* __restrict__ gamma,
    const float* __restrict__ beta)
{
    const int t  = threadIdx.x;
    const int pi = t & 63;
    const int g  = t >> 6;
    const int pos = blockIdx.x * 64 + pi;
    const int b = (pos >= L_SEQ) ? 1 : 0;
    const int l = pos - b * L_SEQ;
    float* col = y + (size_t)b * CDIM * L_SEQ + l;

    float s = 0.f, sq = 0.f;
    for (int c = g * 128; c < g * 128 + 128; c++) {
        const float v = col[(size_t)c * L_SEQ];
        s += v; sq += v * v;
    }
    __shared__ float S1[4][64];
    __shared__ float S2[4][64];
    S1[g][pi] = s; S2[g][pi] = sq;
    __syncthreads();
    if (g == 0) {
        s  = S1[0][pi] + S1[1][pi] + S1[2][pi] + S1[3][pi];
        sq = S2[0][pi] + S2[1][pi] + S2[2][pi] + S2[3][pi];
        const float mu = s * (1.0f / CDIM);
        const float var = sq * (1.0f / CDIM) - mu * mu;
        S1[0][pi] = mu;
        S2[0][pi] = rsqrtf(var + 1e-5f);
    }
    __syncthreads();
    const float mu = S1[0][pi];
    const float rs = S2[0][pi];
    for (int c = g * 128; c < g * 128 + 128; c++) {
        const float v = col[(size_t)c * L_SEQ];
        col[(size_t)c * L_SEQ] = (v - mu) * rs * gamma[c] + beta[c];
    }
}

// ==================================================================
extern "C" void kernel_launch(void* const* d_in, const int* in_sizes, int n_in,
                              void* d_out, int out_size, void* d_ws, size_t ws_size,
                              hipStream_t stream) {
    const float* x    = (const float*)d_in[0];
    const int* mask   = (const int*)d_in[1];   // bool -> int32 per harness convention
    const float* pos  = (const float*)d_in[2];
    const float* Wq   = (const float*)d_in[3];
    const float* bq   = (const float*)d_in[4];
    const float* Wk   = (const float*)d_in[5];
    const float* bk   = (const float*)d_in[6];
    const float* Wv   = (const float*)d_in[7];
    const float* bv   = (const float*)d_in[8];
    const float* Wo   = (const float*)d_in[9];
    const float* bo   = (const float*)d_in[10];
    const float* rel  = (const float*)d_in[11];
    const float* gam  = (const float*)d_in[12];
    const float* bet  = (const float*)d_in[13];

    const size_t per = (size_t)2 * NHEADS * L_SEQ * HD;  // 2359296 floats
    float* ws   = (float*)d_ws;
    float* q_t  = ws;
    float* k_t  = q_t + per;
    float* v_t  = k_t + per;
    float* attn = v_t + per;
    float* y    = (float*)d_out;

    dim3 g1(L_SEQ / 64, CDIM / 64, 2 * 3);
    qkv_gemm<<<g1, 256, 0, stream>>>(x, pos, Wq, bq, Wk, bk, Wv, bv, q_t, k_t, v_t);

    dim3 g2(L_SEQ / 64, 2 * NHEADS);
    flash_attn<<<g2, 256, 0, stream>>>(q_t, k_t, v_t, mask, rel, attn);

    dim3 g3(L_SEQ / 64, CDIM / 64, 2);
    out_gemm<<<g3, 256, 0, stream>>>(attn, Wo, bo, x, y);

    ln_kernel<<<(2 * L_SEQ) / 64, 256, 0, stream>>>(y, gam, bet);
}

// Round 3
// 504.119 us; speedup vs baseline: 1.9828x; 1.9828x over previous
//
#include <hip/hip_runtime.h>
#include <cstdint>

#define L_SEQ 2304
#define CDIM  512
#define NHEADS 8
#define HD    64
#define LL    ((size_t)L_SEQ * L_SEQ)

typedef short  s8v  __attribute__((ext_vector_type(8)));
typedef float  f4v  __attribute__((ext_vector_type(4)));

__device__ __forceinline__ ushort f2bf(float f) {
    union { float f; uint32_t u; } v; v.f = f;
    uint32_t u = v.u;
    uint32_t r = (u + 0x7FFFu + ((u >> 16) & 1u)) >> 16;
    return (ushort)r;
}

// ==================================================================
// QKV projection -> bf16 outputs. q,k in (b,h,l,d); v transposed (b,h,d,l).
// Q pre-scaled by 0.125 (exact pow2). grid (36, 8, 6), block 256.
__global__ __launch_bounds__(256) void qkv_gemm(
    const float* __restrict__ x, const float* __restrict__ pos,
    const float* __restrict__ Wq, const float* __restrict__ bq,
    const float* __restrict__ Wk, const float* __restrict__ bk,
    const float* __restrict__ Wv, const float* __restrict__ bv,
    ushort* __restrict__ q_t, ushort* __restrict__ k_t, ushort* __restrict__ v_t)
{
    const int l0 = blockIdx.x * 64;
    const int o0 = blockIdx.y * 64;
    const int b  = blockIdx.z / 3;
    const int w  = blockIdx.z % 3;
    const float* W    = (w == 0) ? Wq : (w == 1) ? Wk : Wv;
    const float* bias = (w == 0) ? bq : (w == 1) ? bk : bv;

    __shared__ float As[16][68];
    __shared__ float Xs[16][68];

    const int t  = threadIdx.x;
    const int ti = t & 15;
    const int tj = t >> 4;
    float acc[4][4] = {};

    const float* xb = x + (size_t)b * CDIM * L_SEQ;

    for (int c0 = 0; c0 < CDIM; c0 += 16) {
        {
            const int oi = t >> 2;
            const int cc = (t & 3) * 4;
            const float4 wv = *(const float4*)&W[(size_t)(o0 + oi) * CDIM + c0 + cc];
            As[cc + 0][oi] = wv.x;
            As[cc + 1][oi] = wv.y;
            As[cc + 2][oi] = wv.z;
            As[cc + 3][oi] = wv.w;
        }
        {
            const int kk = t >> 4;
            const int j  = (t & 15) * 4;
            const size_t off = (size_t)(c0 + kk) * L_SEQ + l0 + j;
            float4 xv = *(const float4*)&xb[off];
            const float4 pv = *(const float4*)&pos[off];
            xv.x += pv.x; xv.y += pv.y; xv.z += pv.z; xv.w += pv.w;
            *(float4*)&Xs[kk][j] = xv;
        }
        __syncthreads();
        #pragma unroll
        for (int kk = 0; kk < 16; kk++) {
            const float4 a  = *(const float4*)&As[kk][ti * 4];
            const float4 bb = *(const float4*)&Xs[kk][tj * 4];
            const float av[4] = {a.x, a.y, a.z, a.w};
            const float bv4[4] = {bb.x, bb.y, bb.z, bb.w};
            #pragma unroll
            for (int i = 0; i < 4; i++)
                #pragma unroll
                for (int j = 0; j < 4; j++)
                    acc[i][j] += av[i] * bv4[j];
        }
        __syncthreads();
    }

    const int h = o0 >> 6;
    const float4 bi = *(const float4*)&bias[o0 + ti * 4];
    const float bia[4] = {bi.x, bi.y, bi.z, bi.w};

    if (w < 2) {
        // q/k row-major (b,h,l,d), Q scaled by 0.125
        const float sc = (w == 0) ? 0.125f : 1.0f;
        ushort* op = (w == 0 ? q_t : k_t) + ((size_t)b * NHEADS + h) * L_SEQ * HD;
        #pragma unroll
        for (int j = 0; j < 4; j++) {
            const int l = l0 + tj * 4 + j;
            ushort4 st;
            st.x = f2bf((acc[0][j] + bia[0]) * sc);
            st.y = f2bf((acc[1][j] + bia[1]) * sc);
            st.z = f2bf((acc[2][j] + bia[2]) * sc);
            st.w = f2bf((acc[3][j] + bia[3]) * sc);
            *(ushort4*)&op[(size_t)l * HD + ti * 4] = st;
        }
    } else {
        // v transposed (b,h,d,l)
        ushort* op = v_t + ((size_t)b * NHEADS + h) * HD * L_SEQ;
        #pragma unroll
        for (int i = 0; i < 4; i++) {
            const int d = ti * 4 + i;
            ushort4 st;
            st.x = f2bf(acc[i][0] + bia[i]);
            st.y = f2bf(acc[i][1] + bia[i]);
            st.z = f2bf(acc[i][2] + bia[i]);
            st.w = f2bf(acc[i][3] + bia[i]);
            *(ushort4*)&op[(size_t)d * L_SEQ + l0 + tj * 4] = st;
        }
    }
}

// ==================================================================
// MFMA flash attention. Block = 256 threads (4 waves), 64 q-rows of one (b,h).
// Wave w owns q-rows [l0+w*16, +16). K-tile = 64 keys staged to LDS in
// MFMA-fragment order. grid 576 (1D, XCD-swizzled), block 256.
__global__ __launch_bounds__(256) void flash_attn_mfma(
    const ushort* __restrict__ q, const ushort* __restrict__ k,
    const ushort* __restrict__ vt, const int* __restrict__ mask,
    const float* __restrict__ rel_table, float* __restrict__ attn_out)
{
    __shared__ __align__(16) ushort Kf[512 * 8];   // B-frags for S
    __shared__ __align__(16) ushort Vf[512 * 8];   // B-frags for PV
    __shared__ __align__(16) ushort Pb[4 * 16 * 72]; // per-wave P, row-major [16][72]
    __shared__ float rt[65];

    const int t    = threadIdx.x;
    const int id   = blockIdx.x;
    const int h    = id & 7;            // XCD-pinned head
    const int slot = id >> 3;
    const int b    = slot & 1;          // adjacent slots share mask rows (L2 reuse)
    const int qb   = slot >> 1;
    const int bh   = b * NHEADS + h;
    const int l0   = qb * 64;
    const int w    = t >> 6;
    const int lane = t & 63;
    const int n16  = lane & 15;
    const int q4   = lane >> 4;

    if (t < 65) rt[t] = rel_table[h * 65 + t];

    const ushort* qp = q  + (size_t)bh * L_SEQ * HD;
    const ushort* kp = k  + (size_t)bh * L_SEQ * HD;
    const ushort* vp = vt + (size_t)bh * HD * L_SEQ;
    const int*    mp = mask + (size_t)h * LL;

    // Q A-fragments: A[m=lane&15][k=quad*8+j], rows l0+w*16+n16
    const int qrow = l0 + w * 16 + n16;
    const s8v qA0 = *(const s8v*)&qp[(size_t)qrow * HD + q4 * 8];
    const s8v qA1 = *(const s8v*)&qp[(size_t)qrow * HD + 32 + q4 * 8];

    f4v O[4] = {{0.f,0.f,0.f,0.f},{0.f,0.f,0.f,0.f},{0.f,0.f,0.f,0.f},{0.f,0.f,0.f,0.f}};
    float mrun[4] = {-3e38f, -3e38f, -3e38f, -3e38f};
    float lrun[4] = {0.f, 0.f, 0.f, 0.f};

    // precompute this thread's two staging chunk decodes (c = t, t+256)
    int sT[2], sS[2], sQ[2], sN[2];
    #pragma unroll
    for (int cc = 0; cc < 2; cc++) {
        const int c = t + cc * 256;
        const int g = c >> 6;
        sT[cc] = g >> 1; sS[cc] = g & 1;
        sQ[cc] = (c >> 4) & 3; sN[cc] = c & 15;
    }

    const int rowbase = l0 + w * 16 + q4 * 4;   // +r gives the C-layout row

    for (int mt = 0; mt < L_SEQ / 64; mt++) {
        const int mb = mt * 64;
        __syncthreads();   // WAR: previous tile's reads done before restage
        #pragma unroll
        for (int cc = 0; cc < 2; cc++) {
            const int c = t + cc * 256;
            const int key = sT[cc] * 16 + sN[cc];
            const int d0  = sS[cc] * 32 + sQ[cc] * 8;
            *(s8v*)&Kf[c * 8] = *(const s8v*)&kp[(size_t)(mb + key) * HD + d0];
            // V chunk: element j = V[mb + sS*32+sQ*8+j][sT*16+sN] = vt[(sT*16+sN)][mb+...]
            const int dd = sT[cc] * 16 + sN[cc];
            *(s8v*)&Vf[c * 8] = *(const s8v*)&vp[(size_t)dd * L_SEQ + mb + d0];
        }
        __syncthreads();

        // mask loads (issue early; int32 per harness bool convention)
        int mreg[4][4];
        #pragma unroll
        for (int t4 = 0; t4 < 4; t4++)
            #pragma unroll
            for (int r = 0; r < 4; r++)
                mreg[t4][r] = mp[(size_t)(rowbase + r) * L_SEQ + mb + t4 * 16 + n16];

        // S = Q K^T  (C layout: col=lane&15 -> key t4*16+n16, row=q4*4+r)
        f4v S[4];
        #pragma unroll
        for (int t4 = 0; t4 < 4; t4++) {
            const s8v b0 = *(const s8v*)&Kf[((t4 * 2 + 0) * 64 + lane) * 8];
            const s8v b1 = *(const s8v*)&Kf[((t4 * 2 + 1) * 64 + lane) * 8];
            f4v acc = {0.f, 0.f, 0.f, 0.f};
            acc = __builtin_amdgcn_mfma_f32_16x16x32_bf16(qA0, b0, acc, 0, 0, 0);
            acc = __builtin_amdgcn_mfma_f32_16x16x32_bf16(qA1, b1, acc, 0, 0, 0);
            S[t4] = acc;
        }

        // relative positional bias (then mask -> exactly -1e9, matching ref order)
        #pragma unroll
        for (int t4 = 0; t4 < 4; t4++) {
            const int A = (l0 + w * 16) - (mb + t4 * 16);
            if (A >= 47) {
                const float bu = rt[64];
                #pragma unroll
                for (int r = 0; r < 4; r++) S[t4][r] += bu;
            } else if (A <= -47) {
                const float bu = rt[0];
                #pragma unroll
                for (int r = 0; r < 4; r++) S[t4][r] += bu;
            } else {
                #pragma unroll
                for (int r = 0; r < 4; r++) {
                    int dix = A + q4 * 4 + r - n16;
                    dix = min(max(dix, -32), 32) + 32;
                    S[t4][r] += rt[dix];
                }
            }
            #pragma unroll
            for (int r = 0; r < 4; r++)
                if (mreg[t4][r] == 0) S[t4][r] = -1e9f;
        }

        // online softmax per row (row stats replicated over 16 lanes of quad)
        float mx[4];
        #pragma unroll
        for (int r = 0; r < 4; r++) {
            float m0 = fmaxf(fmaxf(S[0][r], S[1][r]), fmaxf(S[2][r], S[3][r]));
            m0 = fmaxf(m0, __shfl_xor(m0, 1));
            m0 = fmaxf(m0, __shfl_xor(m0, 2));
            m0 = fmaxf(m0, __shfl_xor(m0, 4));
            m0 = fmaxf(m0, __shfl_xor(m0, 8));
            mx[r] = m0;
        }
        float al[4];
        #pragma unroll
        for (int r = 0; r < 4; r++) {
            const float mn = fmaxf(mrun[r], mx[r]);
            al[r] = __expf(mrun[r] - mn);
            mrun[r] = mn;
            float sum = 0.f;
            #pragma unroll
            for (int t4 = 0; t4 < 4; t4++) {
                const float p = __expf(S[t4][r] - mn);
                S[t4][r] = p;
                sum += p;
                Pb[w * 1152 + (q4 * 4 + r) * 72 + t4 * 16 + n16] = f2bf(p);
            }
            sum += __shfl_xor(sum, 1);
            sum += __shfl_xor(sum, 2);
            sum += __shfl_xor(sum, 4);
            sum += __shfl_xor(sum, 8);
            lrun[r] = lrun[r] * al[r] + sum;
        }

        // rescale O, then O += P V   (per-wave Pb: same-wave dep, no barrier)
        const s8v pf0 = *(const s8v*)&Pb[w * 1152 + n16 * 72 + q4 * 8];
        const s8v pf1 = *(const s8v*)&Pb[w * 1152 + n16 * 72 + 32 + q4 * 8];
        #pragma unroll
        for (int t4 = 0; t4 < 4; t4++) {
            f4v o = O[t4];
            #pragma unroll
            for (int r = 0; r < 4; r++) o[r] *= al[r];
            const s8v v0 = *(const s8v*)&Vf[((t4 * 2 + 0) * 64 + lane) * 8];
            const s8v v1 = *(const s8v*)&Vf[((t4 * 2 + 1) * 64 + lane) * 8];
            o = __builtin_amdgcn_mfma_f32_16x16x32_bf16(pf0, v0, o, 0, 0, 0);
            o = __builtin_amdgcn_mfma_f32_16x16x32_bf16(pf1, v1, o, 0, 0, 0);
            O[t4] = o;
        }
    }

    float inv[4];
    #pragma unroll
    for (int r = 0; r < 4; r++) inv[r] = 1.0f / lrun[r];
    float* op = attn_out + (size_t)bh * L_SEQ * HD;
    #pragma unroll
    for (int r = 0; r < 4; r++) {
        const size_t row = (size_t)(rowbase + r) * HD;
        #pragma unroll
        for (int t4 = 0; t4 < 4; t4++)
            op[row + t4 * 16 + n16] = O[t4][r] * inv[r];
    }
}

// ==================================================================
// Output projection + bias + residual (fp32). grid (36, 8, 2), block 256.
__global__ __launch_bounds__(256) void out_gemm(
    const float* __restrict__ attn, const float* __restrict__ Wo,
    const float* __restrict__ bo, const float* __restrict__ x,
    float* __restrict__ y)
{
    const int l0 = blockIdx.x * 64;
    const int o0 = blockIdx.y * 64;
    const int b  = blockIdx.z;

    __shared__ float As[16][68];
    __shared__ float Xs[16][68];

    const int t  = threadIdx.x;
    const int ti = t & 15;
    const int tj = t >> 4;
    float acc[4][4] = {};

    const float* ab = attn + (size_t)b * NHEADS * L_SEQ * HD;

    for (int c0 = 0; c0 < CDIM; c0 += 16) {
        {
            const int oi = t >> 2;
            const int cc = (t & 3) * 4;
            const float4 wv = *(const float4*)&Wo[(size_t)(o0 + oi) * CDIM + c0 + cc];
            As[cc + 0][oi] = wv.x;
            As[cc + 1][oi] = wv.y;
            As[cc + 2][oi] = wv.z;
            As[cc + 3][oi] = wv.w;
        }
        {
            const int j   = t & 63;
            const int kkb = (t >> 6) * 4;
            const int c   = c0 + kkb;
            const int hh  = c >> 6;
            const int dd  = c & 63;
            const float4 av = *(const float4*)&ab[((size_t)hh * L_SEQ + l0 + j) * HD + dd];
            Xs[kkb + 0][j] = av.x;
            Xs[kkb + 1][j] = av.y;
            Xs[kkb + 2][j] = av.z;
            Xs[kkb + 3][j] = av.w;
        }
        __syncthreads();
        #pragma unroll
        for (int kk = 0; kk < 16; kk++) {
            const float4 a  = *(const float4*)&As[kk][ti * 4];
            const float4 bb = *(const float4*)&Xs[kk][tj * 4];
            const float av[4] = {a.x, a.y, a.z, a.w};
            const float bv4[4] = {bb.x, bb.y, bb.z, bb.w};
            #pragma unroll
            for (int i = 0; i < 4; i++)
                #pragma unroll
                for (int j = 0; j < 4; j++)
                    acc[i][j] += av[i] * bv4[j];
        }
        __syncthreads();
    }

    const float4 bi = *(const float4*)&bo[o0 + ti * 4];
    const float bia[4] = {bi.x, bi.y, bi.z, bi.w};
    #pragma unroll
    for (int i = 0; i < 4; i++) {
        const int o = o0 + ti * 4 + i;
        const size_t off = ((size_t)b * CDIM + o) * L_SEQ + l0 + tj * 4;
        const float4 xv = *(const float4*)&x[off];
        float4 st;
        st.x = acc[i][0] + bia[i] + xv.x;
        st.y = acc[i][1] + bia[i] + xv.y;
        st.z = acc[i][2] + bia[i] + xv.z;
        st.w = acc[i][3] + bia[i] + xv.w;
        *(float4*)&y[off] = st;
    }
}

// ==================================================================
__global__ __launch_bounds__(256) void ln_kernel(
    float* __restrict__ y, const float* __restrict__ gamma,
    const float* __restrict__ beta)
{
    const int t  = threadIdx.x;
    const int pi = t & 63;
    const int g  = t >> 6;
    const int pos = blockIdx.x * 64 + pi;
    const int b = (pos >= L_SEQ) ? 1 : 0;
    const int l = pos - b * L_SEQ;
    float* col = y + (size_t)b * CDIM * L_SEQ + l;

    float s = 0.f, sq = 0.f;
    for (int c = g * 128; c < g * 128 + 128; c++) {
        const float v = col[(size_t)c * L_SEQ];
        s += v; sq += v * v;
    }
    __shared__ float S1[4][64];
    __shared__ float S2[4][64];
    S1[g][pi] = s; S2[g][pi] = sq;
    __syncthreads();
    if (g == 0) {
        s  = S1[0][pi] + S1[1][pi] + S1[2][pi] + S1[3][pi];
        sq = S2[0][pi] + S2[1][pi] + S2[2][pi] + S2[3][pi];
        const float mu = s * (1.0f / CDIM);
        const float var = sq * (1.0f / CDIM) - mu * mu;
        S1[0][pi] = mu;
        S2[0][pi] = rsqrtf(var + 1e-5f);
    }
    __syncthreads();
    const float mu = S1[0][pi];
    const float rs = S2[0][pi];
    for (int c = g * 128; c < g * 128 + 128; c++) {
        const float v = col[(size_t)c * L_SEQ];
        col[(size_t)c * L_SEQ] = (v - mu) * rs * gamma[c] + beta[c];
    }
}

// ==================================================================
extern "C" void kernel_launch(void* const* d_in, const int* in_sizes, int n_in,
                              void* d_out, int out_size, void* d_ws, size_t ws_size,
                              hipStream_t stream) {
    const float* x    = (const float*)d_in[0];
    const int* mask   = (const int*)d_in[1];
    const float* pos  = (const float*)d_in[2];
    const float* Wq   = (const float*)d_in[3];
    const float* bq   = (const float*)d_in[4];
    const float* Wk   = (const float*)d_in[5];
    const float* bk   = (const float*)d_in[6];
    const float* Wv   = (const float*)d_in[7];
    const float* bv   = (const float*)d_in[8];
    const float* Wo   = (const float*)d_in[9];
    const float* bo   = (const float*)d_in[10];
    const float* rel  = (const float*)d_in[11];
    const float* gam  = (const float*)d_in[12];
    const float* bet  = (const float*)d_in[13];

    const size_t per = (size_t)2 * NHEADS * L_SEQ * HD;  // 2359296 elems
    ushort* qw = (ushort*)d_ws;
    ushort* kw = qw + per;
    ushort* vw = kw + per;
    float* attn = (float*)(vw + per);   // byte offset 14155776 (16B aligned)
    float* y    = (float*)d_out;

    dim3 g1(L_SEQ / 64, CDIM / 64, 2 * 3);
    qkv_gemm<<<g1, 256, 0, stream>>>(x, pos, Wq, bq, Wk, bk, Wv, bv, qw, kw, vw);

    flash_attn_mfma<<<dim3(576), 256, 0, stream>>>(qw, kw, vw, mask, rel, attn);

    dim3 g3(L_SEQ / 64, CDIM / 64, 2);
    out_gemm<<<g3, 256, 0, stream>>>(attn, Wo, bo, x, y);

    ln_kernel<<<(2 * L_SEQ) / 64, 256, 0, stream>>>(y, gam, bet);
}